// Round 1
// baseline (366.999 us; speedup 1.0000x reference)
//
#include <hip/hip_runtime.h>
#include <cstdint>
#include <cstddef>

// Problem constants (from reference): D delays, B batch, E pre, O post
#define DD 16
#define BB 8
#define EE 2048
#define OO 2048

// ---------------------------------------------------------------------------
// Kernel 1: pack coefficients C[e][d][b] = Xd[d,b,e] * (Wshort[d,b,e] + 1)
// Xd/Wshort layout: (d*B+b)*E + e  (coalesced read over i); scattered 4B
// writes (1 MB total, absorbed by L2).
// ---------------------------------------------------------------------------
__global__ void pack_coeffs(const float* __restrict__ Xd,
                            const float* __restrict__ Ws,
                            float* __restrict__ Cpack) {
    int i = blockIdx.x * 256 + threadIdx.x;   // over D*B*E = 262144
    if (i >= DD * BB * EE) return;
    int e  = i & (EE - 1);
    int db = i >> 11;            // i / E
    int d  = db >> 3;            // db / B
    int b  = db & 7;             // db % B
    float x = Xd[i];
    float v = x * (Ws[i] + 1.0f);
    Cpack[((size_t)e * DD + d) * BB + b] = v;
}

// ---------------------------------------------------------------------------
// Kernel 2: per-e bitmask of delays d with any nonzero batch coefficient.
// ---------------------------------------------------------------------------
__global__ void build_mask(const float* __restrict__ Cpack,
                           unsigned* __restrict__ mask) {
    int e = blockIdx.x * 256 + threadIdx.x;
    if (e >= EE) return;
    const float4* c4 = reinterpret_cast<const float4*>(Cpack + (size_t)e * DD * BB);
    unsigned m = 0;
    for (int d = 0; d < DD; ++d) {
        float4 a = c4[d * 2];
        float4 b = c4[d * 2 + 1];
        bool nz = (a.x != 0.f) | (a.y != 0.f) | (a.z != 0.f) | (a.w != 0.f) |
                  (b.x != 0.f) | (b.y != 0.f) | (b.z != 0.f) | (b.w != 0.f);
        m |= (nz ? 1u : 0u) << d;
    }
    mask[e] = m;
}

__device__ __forceinline__ void fma4(float4& a, const float4& x, float s) {
    a.x = fmaf(x.x, s, a.x);
    a.y = fmaf(x.y, s, a.y);
    a.z = fmaf(x.z, s, a.z);
    a.w = fmaf(x.w, s, a.w);
}

// ---------------------------------------------------------------------------
// Main kernel.
// Grid: (8 o-tiles, 64 e-chunks). Block: 256 threads = 4 waves.
// All 4 waves share the o-tile (256 outputs, lane owns 4 consecutive o's);
// each wave handles 8 of the chunk's 32 e's.
// I[b,o] += Weff[e,o] * delaymap[d,e,o] * C[e][d][b], skipping (d,e) rows
// where all 8 batch coefficients are zero (mask-driven, ~66% skipped).
// USE_PACK:  coefficients/mask precomputed in workspace (fast path)
// USE_PART:  write per-chunk partials to ws (deterministic); else atomicAdd.
// ---------------------------------------------------------------------------
template <bool USE_PACK, bool USE_PART>
__global__ __launch_bounds__(256, 2)
void synapse_main(const float* __restrict__ W,
                  const float* __restrict__ S,
                  const float* __restrict__ Xd,
                  const float* __restrict__ Ws,
                  const float* __restrict__ DM,
                  const float* __restrict__ Cpack,
                  const unsigned* __restrict__ mask,
                  float* __restrict__ Pout) {
    const int ot   = blockIdx.x;             // o-tile: 0..7
    const int ch   = blockIdx.y;             // e-chunk: 0..63
    const int wave = threadIdx.x >> 6;       // 0..3
    const int lane = threadIdx.x & 63;
    const int o0   = ot * 256 + lane * 4;    // first of 4 owned o's
    const int e_begin = ch * 32 + wave * 8;

    float4 acc[BB];
#pragma unroll
    for (int b = 0; b < BB; ++b) acc[b] = make_float4(0.f, 0.f, 0.f, 0.f);

    for (int ei = 0; ei < 8; ++ei) {
        const int e = e_begin + ei;

        // Weff tile for this e (issued early; needed with prob ~99.9%)
        float4 w4 = *reinterpret_cast<const float4*>(W + (size_t)e * OO + o0);
        float4 s4 = *reinterpret_cast<const float4*>(S + (size_t)e * OO + o0);
        float4 wf;
        wf.x = w4.x * s4.x; wf.y = w4.y * s4.y;
        wf.z = w4.z * s4.z; wf.w = w4.w * s4.w;

        if (USE_PACK) {
            unsigned m = mask[e];            // wave-uniform
            while (m) {
                const int d = __builtin_ctz(m);
                m &= (m - 1);
                const float4* cp = reinterpret_cast<const float4*>(
                    Cpack + ((size_t)e * DD + d) * BB);
                float4 c0 = cp[0];
                float4 c1 = cp[1];
                float4 dm = *reinterpret_cast<const float4*>(
                    DM + ((size_t)d * EE + e) * OO + o0);
                float4 dw;
                dw.x = dm.x * wf.x; dw.y = dm.y * wf.y;
                dw.z = dm.z * wf.z; dw.w = dm.w * wf.w;
                fma4(acc[0], dw, c0.x); fma4(acc[1], dw, c0.y);
                fma4(acc[2], dw, c0.z); fma4(acc[3], dw, c0.w);
                fma4(acc[4], dw, c1.x); fma4(acc[5], dw, c1.y);
                fma4(acc[6], dw, c1.z); fma4(acc[7], dw, c1.w);
            }
        } else {
            // no-workspace fallback: compute coefficients inline
            for (int d = 0; d < DD; ++d) {
                float c[BB];
                bool nz = false;
#pragma unroll
                for (int b = 0; b < BB; ++b) {
                    size_t idx = (size_t)(d * BB + b) * EE + e;
                    float x = Xd[idx];
                    c[b] = x * (Ws[idx] + 1.0f);
                    nz |= (c[b] != 0.f);
                }
                if (!nz) continue;
                float4 dm = *reinterpret_cast<const float4*>(
                    DM + ((size_t)d * EE + e) * OO + o0);
                float4 dw;
                dw.x = dm.x * wf.x; dw.y = dm.y * wf.y;
                dw.z = dm.z * wf.z; dw.w = dm.w * wf.w;
#pragma unroll
                for (int b = 0; b < BB; ++b) fma4(acc[b], dw, c[b]);
            }
        }
    }

    if (USE_PART) {
        // block-level reduction of the 4 waves' accumulators via LDS,
        // then one deterministic partial slice per (chunk, b, o-tile).
        __shared__ __align__(16) float red[4][BB][256];
#pragma unroll
        for (int b = 0; b < BB; ++b)
            *reinterpret_cast<float4*>(&red[wave][b][lane * 4]) = acc[b];
        __syncthreads();
        const int t = threadIdx.x;           // o index within tile
#pragma unroll
        for (int b = 0; b < BB; ++b) {
            float s = red[0][b][t] + red[1][b][t] + red[2][b][t] + red[3][b][t];
            Pout[((size_t)ch * BB + b) * OO + ot * 256 + t] = s;
        }
    } else {
#pragma unroll
        for (int b = 0; b < BB; ++b) {
            float* op = Pout + (size_t)b * OO + o0;
            atomicAdd(op + 0, acc[b].x);
            atomicAdd(op + 1, acc[b].y);
            atomicAdd(op + 2, acc[b].z);
            atomicAdd(op + 3, acc[b].w);
        }
    }
}

// ---------------------------------------------------------------------------
// Kernel 4: reduce 64 partial slices -> out[b*O + o]
// ---------------------------------------------------------------------------
__global__ void reduce_partials(const float* __restrict__ P,
                                float* __restrict__ out) {
    int i = blockIdx.x * 256 + threadIdx.x;  // over B*O = 16384
    if (i >= BB * OO) return;
    int b = i >> 11;          // i / O
    int o = i & (OO - 1);     // i % O
    float s = 0.f;
    for (int ch = 0; ch < 64; ++ch)
        s += P[((size_t)ch * BB + b) * OO + o];
    out[(size_t)b * OO + o] = s;
}

extern "C" void kernel_launch(void* const* d_in, const int* in_sizes, int n_in,
                              void* d_out, int out_size, void* d_ws, size_t ws_size,
                              hipStream_t stream) {
    const float* W  = (const float*)d_in[0];
    const float* S  = (const float*)d_in[1];
    const float* Xd = (const float*)d_in[2];
    const float* Ws = (const float*)d_in[3];
    const float* DM = (const float*)d_in[4];
    float* out = (float*)d_out;

    const size_t packBytes = (size_t)EE * DD * BB * sizeof(float);   // 1 MiB
    const size_t maskBytes = (size_t)EE * sizeof(unsigned);          // 8 KiB
    const size_t partBytes = (size_t)64 * BB * OO * sizeof(float);   // 4 MiB

    char* ws = (char*)d_ws;
    const bool canPack = ws_size >= packBytes + maskBytes;
    const bool canPart = ws_size >= packBytes + maskBytes + partBytes;

    dim3 grid(8, 64), blk(256);

    if (canPart) {
        float*    Cp = (float*)ws;
        unsigned* mk = (unsigned*)(ws + packBytes);
        float*    P  = (float*)(ws + packBytes + maskBytes);
        pack_coeffs<<<(DD * BB * EE + 255) / 256, 256, 0, stream>>>(Xd, Ws, Cp);
        build_mask<<<(EE + 255) / 256, 256, 0, stream>>>(Cp, mk);
        synapse_main<true, true><<<grid, blk, 0, stream>>>(W, S, Xd, Ws, DM, Cp, mk, P);
        reduce_partials<<<(BB * OO + 255) / 256, 256, 0, stream>>>(P, out);
    } else if (canPack) {
        float*    Cp = (float*)ws;
        unsigned* mk = (unsigned*)(ws + packBytes);
        hipMemsetAsync(out, 0, (size_t)BB * OO * sizeof(float), stream);
        pack_coeffs<<<(DD * BB * EE + 255) / 256, 256, 0, stream>>>(Xd, Ws, Cp);
        build_mask<<<(EE + 255) / 256, 256, 0, stream>>>(Cp, mk);
        synapse_main<true, false><<<grid, blk, 0, stream>>>(W, S, Xd, Ws, DM, Cp, mk, out);
    } else {
        hipMemsetAsync(out, 0, (size_t)BB * OO * sizeof(float), stream);
        synapse_main<false, false><<<grid, blk, 0, stream>>>(W, S, Xd, Ws, DM,
                                                             nullptr, nullptr, out);
    }
}